// Round 10
// baseline (652.541 us; speedup 1.0000x reference)
//
#include <hip/hip_runtime.h>
#include <hip/hip_bf16.h>
#include <math.h>

// TemporalSkeletonBranch — Round 10: cheap gelu + 4 blocks/CU.
// R9 (374us): ~50% issue-idle; gelu = ~1200 of ~1500 VALU inst/thread; LDS 41.5KB
// blocks the 4-block/CU tier. R10: gelu = x - x*rcp(2^u + 1) (8 ops, clamp-free);
// Pt re-laid as [f][kchunk][n][8] B-frag chunks (16KB, 16B-aligned b128) ->
// LDS ~38.3KB -> 4 blocks/CU; __launch_bounds__(256,4) pins VGPR<=128.

#define NJ 33
#define NF 52
#define NH 128
#define NT 256
#define NB 64
#define NSAMP (NB*NT)       // 16384
#define SPB 2               // samples per block
#define NBLKS (NSAMP/SPB)   // 8192
#define HSTR 136            // hb row stride (halves)

typedef unsigned short u16;
typedef _Float16 f16;
typedef f16   half8 __attribute__((ext_vector_type(8)));
typedef f16   h2    __attribute__((ext_vector_type(2)));
typedef float f32x4 __attribute__((ext_vector_type(4)));

// ---- workspace layout (R8-proven) ----
#define HO_W0    0            // [n=128][k=64]
#define HO_S0    8192
#define HO_W1    16384        // [n=128][k=128]
#define HO_W2    32768
#define HO_TW1   49152
#define HO_ADJ32 65536        // [32][32] f16, rows/cols 25..31 = 0
#define H_TOTAL  66560
#define FO_BASE  (H_TOTAL/2)  // 33280 floats
#define FO_A0    (FO_BASE+0)  // [L*256 + {A:c, D:128+c}]
#define FO_SB0   (FO_BASE+768)
#define FO_TB1   (FO_BASE+896)
#define FO_TW2   (FO_BASE+1024)
#define FO_XT    (FO_BASE+1152)
#define FO_SC    (FO_XT + NSAMP*NH)

// Pt chunked B-frag layout: [f][kchunk(0..3)][n(0..127)][8]
#define PT2(fF,qd,n) ((((fF)*4+(qd))*128+(n))*8)

__device__ __forceinline__ float bf2f(u16 u) { return __uint_as_float(((unsigned)u) << 16); }
__device__ __forceinline__ float ldv(const void* p, long i, int f) {
    float r;
    if (f) r = bf2f(((const u16*)p)[i]);
    else   r = ((const float*)p)[i];
    return r;
}
__device__ int detect_bf16(const void* p) {
    const u16* q = (const u16*)p;
    int nz = 0, ok = 0;
#pragma unroll
    for (int k = 0; k < 64; k++) {
        u16 u = q[k];
        if (u & 0x7FFF) {
            nz++;
            int e = (u >> 7) & 0xFF;
            ok += (e >= 0x40 && e <= 0xBF) ? 1 : 0;
        }
    }
    return (nz == 0) || (ok * 20 >= nz * 19);
}

// tanh-gelu, 8-op clamp-free form: gelu = x - x * rcp(2^u + 1),
// u = x*(a*x^2 + b). x->-inf: e->0, rcp(1)=1 -> 0 ✓; x->+inf: rcp(inf)=0 -> x ✓.
__device__ __forceinline__ float gelu_t(float x) {
    float u = x * fmaf(x * x, 0.10294324f, 2.3022082f);
#if __has_builtin(__builtin_amdgcn_exp2f)
    float e = __builtin_amdgcn_exp2f(u);
#else
    float e = exp2f(u);
#endif
#if __has_builtin(__builtin_amdgcn_rcpf)
    return x - x * __builtin_amdgcn_rcpf(e + 1.f);
#else
    return x - x / (e + 1.f);
#endif
}

#define MFMA16(a, b, c) __builtin_amdgcn_mfma_f32_16x16x32_f16(a, b, c, 0, 0, 0)

// ---- prep: dtype detect + fp16 transposed weights + folded BN + adj32 (proven) ----
__global__ __launch_bounds__(256) void prep(
    const void* adj,
    const void* W0, const void* b0, const void* S0, const void* sb0,
    const void* g0, const void* be0, const void* m0, const void* v0,
    const void* W1, const void* b1, const void* g1, const void* be1, const void* m1, const void* v1,
    const void* W2, const void* b2, const void* g2, const void* be2, const void* m2, const void* v2,
    const void* tW1, const void* tb1, const void* tW2,
    void* ws)
{
    f16* H = (f16*)ws; float* F = (float*)ws;
    const int bi = blockIdx.x, t = threadIdx.x;
    if (bi == 0) {
        const int fW = detect_bf16(W0), fS = detect_bf16(S0);
        for (int i = t; i < NF * 128; i += 256) {
            int k = i >> 7, n = i & 127;
            H[HO_W0 + n * 64 + k] = (f16)ldv(W0, i, fW);
            H[HO_S0 + n * 64 + k] = (f16)ldv(S0, i, fS);
        }
        for (int i = t; i < 128 * 16; i += 256) {
            int n = i >> 4, k = 48 + (i & 15);
            if (k >= NF) { H[HO_W0 + n * 64 + k] = (f16)0.f; H[HO_S0 + n * 64 + k] = (f16)0.f; }
        }
    } else if (bi == 1) {
        const int f = detect_bf16(W1);
        for (int i = t; i < 128 * 128; i += 256) {
            int k = i >> 7, n = i & 127;
            H[HO_W1 + n * 128 + k] = (f16)ldv(W1, i, f);
        }
    } else if (bi == 2) {
        const int f = detect_bf16(W2);
        for (int i = t; i < 128 * 128; i += 256) {
            int k = i >> 7, n = i & 127;
            H[HO_W2 + n * 128 + k] = (f16)ldv(W2, i, f);
        }
    } else if (bi == 3) {
        const int f = detect_bf16(tW1);
        for (int i = t; i < 128 * 128; i += 256) {
            int k = i >> 7, n = i & 127;
            H[HO_TW1 + n * 128 + k] = (f16)ldv(tW1, i, f);
        }
    } else {
        if (t < 128) {
            int c = t;
            {
                float g = ldv(g0,c,detect_bf16(g0)), be = ldv(be0,c,detect_bf16(be0));
                float m = ldv(m0,c,detect_bf16(m0)), v = ldv(v0,c,detect_bf16(v0));
                float b = ldv(b0,c,detect_bf16(b0));
                float A = g * rsqrtf(v + 1e-5f);
                F[FO_A0 + 0*256 + c] = A; F[FO_A0 + 0*256 + 128 + c] = (b - m)*A + be;
            }
            {
                float g = ldv(g1,c,detect_bf16(g1)), be = ldv(be1,c,detect_bf16(be1));
                float m = ldv(m1,c,detect_bf16(m1)), v = ldv(v1,c,detect_bf16(v1));
                float b = ldv(b1,c,detect_bf16(b1));
                float A = g * rsqrtf(v + 1e-5f);
                F[FO_A0 + 1*256 + c] = A; F[FO_A0 + 1*256 + 128 + c] = (b - m)*A + be;
            }
            {
                float g = ldv(g2,c,detect_bf16(g2)), be = ldv(be2,c,detect_bf16(be2));
                float m = ldv(m2,c,detect_bf16(m2)), v = ldv(v2,c,detect_bf16(v2));
                float b = ldv(b2,c,detect_bf16(b2));
                float A = g * rsqrtf(v + 1e-5f);
                F[FO_A0 + 2*256 + c] = A; F[FO_A0 + 2*256 + 128 + c] = (b - m)*A + be;
            }
            F[FO_SB0 + c] = ldv(sb0, c, detect_bf16(sb0));
            F[FO_TB1 + c] = ldv(tb1, c, detect_bf16(tb1));
            F[FO_TW2 + c] = ldv(tW2, c, detect_bf16(tW2));
        }
        const int fA = detect_bf16(adj);
        for (int i = t; i < 1024; i += 256) {
            int r = i >> 5, c = i & 31;
            float v = (r < 25 && c < 25) ? ldv(adj, (long)r*NJ + c, fA) : 0.f;
            H[HO_ADJ32 + i] = (f16)v;
        }
    }
}

// ==== Pt write: P joint-rows 0..24 -> chunked B-layout (pairs never cross chunks) ====
#define PTWRITE(ACC)                                                            \
    _Pragma("unroll")                                                           \
    for (int mt = 0; mt < 4; mt++) {                                            \
        const int fF = mt >> 1;                                                 \
        const int jb = (mt & 1) * 16;                                           \
        _Pragma("unroll")                                                       \
        for (int nt = 0; nt < 2; nt++) {                                        \
            const int cc = nt ? c1 : c0;                                        \
            _Pragma("unroll")                                                   \
            for (int r2 = 0; r2 < 4; r2 += 2) {                                 \
                int j0 = jb + q*4 + r2;                                         \
                f16* pp = Pt + PT2(fF, j0 >> 3, cc) + (j0 & 7);                 \
                if (j0 + 1 < 25) {                                              \
                    h2 v2w = { (f16)ACC[mt][nt][r2], (f16)ACC[mt][nt][r2+1] };  \
                    *(h2*)pp = v2w;                                             \
                } else if (j0 < 25) {                                           \
                    *pp = (f16)ACC[mt][nt][r2];                                 \
                }                                                               \
            }                                                                   \
        }                                                                       \
    }

// ==== adjmix MFMA + register epilogue: hz/h32 updated in place ====
#define ADJEPI(L, WRHB) {                                                       \
    f32x4 zac[2][2][2];                                                         \
    _Pragma("unroll")                                                           \
    for (int fF = 0; fF < 2; fF++) {                                            \
        _Pragma("unroll")                                                       \
        for (int nt = 0; nt < 2; nt++) {                                        \
            half8 bz = *(const half8*)(Pt + PT2(fF, q, (nt?c1:c0)));            \
            zac[fF][0][nt] = MFMA16(afadj0, bz, z4);                            \
            zac[fF][1][nt] = MFMA16(afadj1, bz, z4);                            \
        }                                                                       \
    }                                                                           \
    _Pragma("unroll")                                                           \
    for (int nt = 0; nt < 2; nt++) {                                            \
        const int cc = nt ? c1 : c0;                                            \
        const float Av = rA[L][nt], Dv = rD[L][nt];                             \
        _Pragma("unroll")                                                       \
        for (int fF = 0; fF < 2; fF++) {                                        \
            _Pragma("unroll")                                                   \
            for (int m2 = 0; m2 < 2; m2++) {                                    \
                _Pragma("unroll")                                               \
                for (int r4 = 0; r4 < 4; r4++) {                                \
                    float zv = (m2 == 0) ? zac[fF][0][nt][r4]                   \
                             : (jlt[r4] ? zac[fF][1][nt][r4]                    \
                                        : acc[2*fF+1][nt][r4]);                 \
                    float hnew = gelu_t(fmaf(zv, Av, Dv)) + hz[fF][m2][nt][r4]; \
                    hz[fF][m2][nt][r4] = hnew;                                  \
                    if (WRHB)                                                   \
                        hb[((2*fF+m2)*16 + q*4 + r4)*HSTR + cc] = (f16)hnew;    \
                }                                                               \
            }                                                                   \
            {                                                                   \
                float hnew = gelu_t(fmaf(acc[4][nt][fF], Av, Dv)) + h32[fF][nt];\
                h32[fF][nt] = (q == 0) ? hnew : 0.f;                            \
                if (WRHB && q == 0)                                             \
                    hb[(64 + fF)*HSTR + cc] = (f16)hnew;                        \
            }                                                                   \
        }                                                                       \
    }                                                                           \
}

// ==== main GEMM over K=128 weights, 5 M-tiles ====
#define GEMM128(WOFF)                                                           \
    {                                                                           \
        half8 bf[2][4];                                                         \
        _Pragma("unroll")                                                       \
        for (int nt = 0; nt < 2; nt++)                                          \
            _Pragma("unroll")                                                   \
            for (int ks = 0; ks < 4; ks++)                                      \
                bf[nt][ks] = *(const half8*)(HW + (WOFF) + (nt?c1:c0)*128 + ks*32 + q*8); \
        _Pragma("unroll")                                                       \
        for (int mt = 0; mt < 5; mt++) { acc[mt][0] = z4; acc[mt][1] = z4; }    \
        _Pragma("unroll")                                                       \
        for (int mt = 0; mt < 5; mt++) {                                        \
            const int m = mt*16 + ml;                                           \
            _Pragma("unroll")                                                   \
            for (int ks = 0; ks < 4; ks++) {                                    \
                half8 af = *(const half8*)(hb + m*HSTR + ks*32 + q*8);          \
                acc[mt][0] = MFMA16(af, bf[0][ks], acc[mt][0]);                 \
                acc[mt][1] = MFMA16(af, bf[1][ks], acc[mt][1]);                 \
            }                                                                   \
        }                                                                       \
    }

__global__ __launch_bounds__(256, 4) void gcn_mfma(const void* __restrict__ x,
                                                   void* __restrict__ ws)
{
    const f16* HW = (const f16*)ws;
    float* F = (float*)ws;
    float* xt_g = F + FO_XT;
    float* sc_g = F + FO_SC;

    __shared__ __align__(16) f16 hb[80 * HSTR];       // 21.76 KB
    __shared__ __align__(16) f16 Pt[2 * 4 * 128 * 8]; // 16.0 KB
    __shared__ float rbuf4[4];
    __shared__ int sfx;
    float* xtb = (float*)Pt;        // alias; used only after ADJEPI(2)+sync

    const int t = threadIdx.x, lane = t & 63, wv = t >> 6;
    const int q = lane >> 4, ml = lane & 15;
    const int n0 = wv * 32;
    const int c0 = n0 + ml, c1 = n0 + 16 + ml;
    const f32x4 z4 = {0.f, 0.f, 0.f, 0.f};
    const bool jlt[4] = { q <= 2, q <= 1, q <= 1, q <= 1 };   // 16+q*4+r4 < 25
    const half8 zero8 = {(f16)0.f,(f16)0.f,(f16)0.f,(f16)0.f,(f16)0.f,(f16)0.f,(f16)0.f,(f16)0.f};

    if (t == 0) sfx = detect_bf16(x);
    // zero Pt chunk 3 (k 24..31; k=24 rewritten per layer, 25..31 must stay 0)
    {
        int fF = t >> 7, n = t & 127;
        *(half8*)(Pt + PT2(fF, 3, n)) = zero8;
    }

    // hoisted per-channel BN constants + sb0
    float rA[3][2], rD[3][2];
#pragma unroll
    for (int L = 0; L < 3; L++) {
        rA[L][0] = F[FO_A0 + L*256 + c0];        rA[L][1] = F[FO_A0 + L*256 + c1];
        rD[L][0] = F[FO_A0 + L*256 + 128 + c0];  rD[L][1] = F[FO_A0 + L*256 + 128 + c1];
    }
    const float sb0a = F[FO_SB0 + c0], sb0b = F[FO_SB0 + c1];
    // adjacency A-frags (rows ml and 16+ml), hoisted for all 3 layers
    half8 afadj0 = *(const half8*)(HW + HO_ADJ32 + ml*32 + q*8);
    half8 afadj1 = *(const half8*)(HW + HO_ADJ32 + (16+ml)*32 + q*8);
    __syncthreads();

    // ---- stage x -> hb: frame f j<32 -> row f*32+j; j==32 -> row 64+f ----
    {
        const int fX = sfx;
        const long xb = (long)blockIdx.x * (SPB * NJ * NF);
#pragma unroll 1
        for (int it = 0; it < 3; it++) {
            int g = t + it * 256;
            if (g < 66 * 8) {
                int r = g >> 3, blk = g & 7;
                int fF = (r >= 33) ? 1 : 0;
                int j = r - 33 * fF;
                int fr = (j < 32) ? (fF * 32 + j) : (64 + fF);
                half8 o;
                if (!fX) {
                    const float* base = (const float*)x + xb + (long)r * NF + blk * 8;
                    if (blk < 6) {
                        float4 v0 = *(const float4*)base;
                        float4 v1 = *(const float4*)(base + 4);
                        o[0]=(f16)v0.x; o[1]=(f16)v0.y; o[2]=(f16)v0.z; o[3]=(f16)v0.w;
                        o[4]=(f16)v1.x; o[5]=(f16)v1.y; o[6]=(f16)v1.z; o[7]=(f16)v1.w;
                    } else if (blk == 6) {
                        float4 v0 = *(const float4*)base;
                        o = zero8;
                        o[0]=(f16)v0.x; o[1]=(f16)v0.y; o[2]=(f16)v0.z; o[3]=(f16)v0.w;
                    } else o = zero8;
                } else {
                    long rb = xb + (long)r * NF;
#pragma unroll
                    for (int i = 0; i < 8; i++) {
                        int cx = blk * 8 + i;
                        o[i] = (f16)(cx < NF ? bf2f(((const u16*)x)[rb + cx]) : 0.f);
                    }
                }
                *(half8*)(hb + fr * HSTR + blk * 8) = o;
            }
        }
    }
    __syncthreads();

    f32x4 acc[5][2];
    float hz[2][2][2][4];   // [frame][m2][nt][r4] — h carried in registers
    float h32[2][2];

    // ================= layer 0 (K=64): P = x@W0, skip = x@S0 =================
    {
        half8 bw[2][2], bs[2][2];
#pragma unroll
        for (int nt = 0; nt < 2; nt++) {
            int n = nt ? c1 : c0;
#pragma unroll
            for (int ks = 0; ks < 2; ks++) {
                bw[nt][ks] = *(const half8*)(HW + HO_W0 + n*64 + ks*32 + q*8);
                bs[nt][ks] = *(const half8*)(HW + HO_S0 + n*64 + ks*32 + q*8);
            }
        }
        f32x4 acs[5][2];
#pragma unroll
        for (int mt = 0; mt < 5; mt++) { acc[mt][0]=z4; acc[mt][1]=z4; acs[mt][0]=z4; acs[mt][1]=z4; }
#pragma unroll
        for (int mt = 0; mt < 5; mt++) {
            const int m = mt*16 + ml;
            half8 a0 = *(const half8*)(hb + m*HSTR + q*8);
            half8 a1 = *(const half8*)(hb + m*HSTR + 32 + q*8);
            acc[mt][0] = MFMA16(a0, bw[0][0], acc[mt][0]);
            acc[mt][0] = MFMA16(a1, bw[0][1], acc[mt][0]);
            acc[mt][1] = MFMA16(a0, bw[1][0], acc[mt][1]);
            acc[mt][1] = MFMA16(a1, bw[1][1], acc[mt][1]);
            acs[mt][0] = MFMA16(a0, bs[0][0], acs[mt][0]);
            acs[mt][0] = MFMA16(a1, bs[0][1], acs[mt][0]);
            acs[mt][1] = MFMA16(a0, bs[1][0], acs[mt][1]);
            acs[mt][1] = MFMA16(a1, bs[1][1], acs[mt][1]);
        }
        __syncthreads();               // all x A-reads done before hb/Pt writes
        PTWRITE(acc)
        // seed hz/h32 with skip + sb0
#pragma unroll
        for (int fF = 0; fF < 2; fF++)
#pragma unroll
            for (int m2 = 0; m2 < 2; m2++)
#pragma unroll
                for (int nt = 0; nt < 2; nt++)
#pragma unroll
                    for (int r4 = 0; r4 < 4; r4++)
                        hz[fF][m2][nt][r4] = acs[2*fF+m2][nt][r4] + (nt ? sb0b : sb0a);
#pragma unroll
        for (int fF = 0; fF < 2; fF++)
#pragma unroll
            for (int nt = 0; nt < 2; nt++)
                h32[fF][nt] = (q == 0) ? (acs[4][nt][fF] + (nt ? sb0b : sb0a)) : 0.f;
        ADJEPI(0, 1)
        __syncthreads();
    }

    // ================= layer 1 =================
    GEMM128(HO_W1)
    __syncthreads();
    PTWRITE(acc)
    ADJEPI(1, 1)
    __syncthreads();

    // ================= layer 2 (no hb writes needed) =================
    GEMM128(HO_W2)
    __syncthreads();
    PTWRITE(acc)
    ADJEPI(2, 0)
    __syncthreads();                   // Pt reads done before xtb alias writes

    // ================= mean over joints (from regs) + score MLP =================
#pragma unroll
    for (int fF = 0; fF < 2; fF++)
#pragma unroll
        for (int nt = 0; nt < 2; nt++) {
            float s = h32[fF][nt];
#pragma unroll
            for (int m2 = 0; m2 < 2; m2++)
#pragma unroll
                for (int r4 = 0; r4 < 4; r4++) s += hz[fF][m2][nt][r4];
            s += __shfl_xor(s, 16, 64);
            s += __shfl_xor(s, 32, 64);
            float xtc = s * (1.0f / 33.0f);
            if (q == 0) {
                int cc = nt ? c1 : c0;
                xtb[fF * 128 + cc] = xtc;
                xt_g[((long)blockIdx.x * SPB + fF) * NH + cc] = xtc;
            }
        }
    __syncthreads();

    {
        const int fF = t >> 7, c = t & 127;
        float u = 0.f;
#pragma unroll
        for (int kk = 0; kk < 16; kk++) {
            half8 wv8 = *(const half8*)(HW + HO_TW1 + c*128 + kk*8);
#pragma unroll
            for (int i = 0; i < 8; i++)
                u = fmaf(xtb[fF*128 + kk*8 + i], (float)wv8[i], u);
        }
        float r = gelu_t(u + F[FO_TB1 + c]) * F[FO_TW2 + c];  // tb2 omitted (shift-inv)
#pragma unroll
        for (int off = 32; off > 0; off >>= 1) r += __shfl_xor(r, off, 64);
        if (lane == 0) rbuf4[wv] = r;
        __syncthreads();
        if (t == 0) {
            sc_g[blockIdx.x * SPB + 0] = rbuf4[0] + rbuf4[1];
            sc_g[blockIdx.x * SPB + 1] = rbuf4[2] + rbuf4[3];
        }
    }
}

// ---- softmax over T + weighted sum -> out[B,H]; shuffle reductions (proven) ----
__global__ __launch_bounds__(256) void attn_pool(
    const void* __restrict__ x,
    const float* __restrict__ xt_ws, const float* __restrict__ score_ws,
    void* __restrict__ out)
{
    __shared__ float ew[NT];
    __shared__ float red[8];
    __shared__ float pb[256];
    __shared__ int sfx2;
    const int t = threadIdx.x, lane = t & 63, wv = t >> 6;
    const int b = blockIdx.x >> 2, qr = blockIdx.x & 3;

    if (t == 0) sfx2 = detect_bf16(x);
    float sv = score_ws[b * NT + t];
    float m = sv;
#pragma unroll
    for (int off = 32; off > 0; off >>= 1) m = fmaxf(m, __shfl_xor(m, off, 64));
    if (lane == 0) red[wv] = m;
    __syncthreads();
    float mx = fmaxf(fmaxf(red[0], red[1]), fmaxf(red[2], red[3]));
    float e = __expf(sv - mx);
    ew[t] = e;
    float d = e;
#pragma unroll
    for (int off = 32; off > 0; off >>= 1) d += __shfl_xor(d, off, 64);
    if (lane == 0) red[4 + wv] = d;
    __syncthreads();
    float den = red[4] + red[5] + red[6] + red[7];

    const int cl = t & 31, ch = t >> 5;
    const int c = qr * 32 + cl;
    float a = 0.f;
#pragma unroll 4
    for (int i = ch * 32; i < ch * 32 + 32; i++)
        a = fmaf(ew[i], xt_ws[((long)b * NT + i) * NH + c], a);
    pb[t] = a;
    __syncthreads();
    if (t < 128) pb[t] += pb[t + 128];
    __syncthreads();
    if (t < 64) pb[t] += pb[t + 64];
    __syncthreads();
    if (t < 32) {
        float r = (pb[t] + pb[t + 32]) / den;
        if (sfx2) ((__hip_bfloat16*)out)[b * NH + qr * 32 + t] = __float2bfloat16(r);
        else      ((float*)out)[b * NH + qr * 32 + t] = r;
    }
}

extern "C" void kernel_launch(void* const* d_in, const int* in_sizes, int n_in,
                              void* d_out, int out_size, void* d_ws, size_t ws_size,
                              hipStream_t stream) {
    prep<<<5, 256, 0, stream>>>(
        d_in[1],
        d_in[2], d_in[3], d_in[4], d_in[5],
        d_in[6], d_in[7], d_in[8], d_in[9],
        d_in[10], d_in[11], d_in[12], d_in[13], d_in[14], d_in[15],
        d_in[16], d_in[17], d_in[18], d_in[19], d_in[20], d_in[21],
        d_in[22], d_in[23], d_in[24],
        d_ws);
    gcn_mfma<<<NBLKS, 256, 0, stream>>>(d_in[0], d_ws);
    float* F = (float*)d_ws;
    attn_pool<<<NB * 4, 256, 0, stream>>>(d_in[0], F + FO_XT, F + FO_SC, d_out);
}